// Round 6
// baseline (207.145 us; speedup 1.0000x reference)
//
#include <hip/hip_runtime.h>

#define HIDDEN 64
#define HALFD  32
#define VOCAB  64
#define BATCH  256
#define SEQLEN 2048

#define RLF(v, sl) __int_as_float(__builtin_amdgcn_readlane(__float_as_int(v), (sl)))
#define RLI(v, sl) __builtin_amdgcn_readlane((v), (sl))
// lane-j broadcast within each 32-lane half (valid: value is 16- or 8-periodic)
#define SWZF(v, j) __int_as_float(__builtin_amdgcn_ds_swizzle(__float_as_int(v), ((j) << 5)))
// lane -> lane&7 within each 32-half (and_mask=7, or=0, xor=0)
#define SWZE(v)    __int_as_float(__builtin_amdgcn_ds_swizzle(__float_as_int(v), 0x0007))
#define GIX(j,m) (((j)==0?0:(j)==1?7:(j)==2?13:(j)==3?18:(j)==4?22:(j)==5?25:27) + (m) - (j) - 1)
#define OM(m) (((m)*((m)+1))>>1)

// ---------------------------------------------------------------------------
// Kernel 1: per-token vocab tables (R20 layout, known-passing).
//   ws[0    ..2047]  ks_voc [64][32]   ws[2048..4095] ke_voc
//   ws[4096 ..6143]  vs_voc           ws[6144..8191] ve_voc
//   ws[8192 ..16383] Gs,Ge [2][64][64]
// ---------------------------------------------------------------------------
__global__ __launch_bounds__(256) void vocab_kernel(
    const float* __restrict__ embed, const float* __restrict__ W1, const float* __restrict__ b1,
    const float* __restrict__ W2, const float* __restrict__ b2,
    const float* __restrict__ ln_g, const float* __restrict__ ln_b,
    const float* __restrict__ Ws, const float* __restrict__ bs,
    const float* __restrict__ We, const float* __restrict__ be,
    float* __restrict__ ws)
{
    const int v = blockIdx.x;
    const int tid = threadIdx.x;

    __shared__ float e_s[64];
    __shared__ float W1_s[128][65];
    __shared__ float W2_s[64][129];
    __shared__ float Wse_s[64][65];
    __shared__ float a1_s[128];
    __shared__ float h_s[64];

    if (tid < 64) e_s[tid] = embed[v * 64 + tid];
    {
        const float4* src = (const float4*)W1;
        for (int i = tid; i < 2048; i += 256) {
            float4 x4 = src[i];
            const int e = i << 2, r = e >> 6, c = e & 63;
            W1_s[r][c] = x4.x; W1_s[r][c+1] = x4.y; W1_s[r][c+2] = x4.z; W1_s[r][c+3] = x4.w;
        }
    }
    __syncthreads();

    if (tid < 128) {
        float p0 = b1[tid], p1 = 0.f, p2 = 0.f, p3 = 0.f;
        #pragma unroll
        for (int m = 0; m < 64; m += 4) {
            p0 = fmaf(e_s[m],   W1_s[tid][m],   p0);
            p1 = fmaf(e_s[m+1], W1_s[tid][m+1], p1);
            p2 = fmaf(e_s[m+2], W1_s[tid][m+2], p2);
            p3 = fmaf(e_s[m+3], W1_s[tid][m+3], p3);
        }
        a1_s[tid] = fmaxf((p0 + p1) + (p2 + p3), 0.0f);
    } else {
        const float4* src = (const float4*)W2;
        for (int i = tid - 128; i < 2048; i += 128) {
            float4 x4 = src[i];
            const int e = i << 2, r = e >> 7, c = e & 127;
            W2_s[r][c] = x4.x; W2_s[r][c+1] = x4.y; W2_s[r][c+2] = x4.z; W2_s[r][c+3] = x4.w;
        }
    }
    __syncthreads();

    if (tid < 64) {
        float f0 = b2[tid], f1 = 0.f, f2 = 0.f, f3 = 0.f;
        #pragma unroll
        for (int m = 0; m < 128; m += 4) {
            f0 = fmaf(a1_s[m],   W2_s[tid][m],   f0);
            f1 = fmaf(a1_s[m+1], W2_s[tid][m+1], f1);
            f2 = fmaf(a1_s[m+2], W2_s[tid][m+2], f2);
            f3 = fmaf(a1_s[m+3], W2_s[tid][m+3], f3);
        }
        float x = e_s[tid] + ((f0 + f1) + (f2 + f3));
        float s = x, s2 = x * x;
        #pragma unroll
        for (int off = 32; off >= 1; off >>= 1) {
            s  += __shfl_xor(s,  off, 64);
            s2 += __shfl_xor(s2, off, 64);
        }
        float mu  = s * (1.0f / 64.0f);
        float var = s2 * (1.0f / 64.0f) - mu * mu;
        h_s[tid] = (x - mu) * rsqrtf(var + 1e-5f) * ln_g[tid] + ln_b[tid];
    } else if (tid < 192) {
        const int t2 = tid - 64;
        const float4* s1 = (const float4*)Ws;
        const float4* s2 = (const float4*)We;
        for (int i = t2; i < 512; i += 128) {
            float4 x4 = s1[i];
            const int e = i << 2, r = e >> 6, c = e & 63;
            Wse_s[r][c] = x4.x; Wse_s[r][c+1] = x4.y; Wse_s[r][c+2] = x4.z; Wse_s[r][c+3] = x4.w;
        }
        for (int i = t2; i < 512; i += 128) {
            float4 x4 = s2[i];
            const int e = i << 2, r = e >> 6, c = e & 63;
            Wse_s[32+r][c] = x4.x; Wse_s[32+r][c+1] = x4.y; Wse_s[32+r][c+2] = x4.z; Wse_s[32+r][c+3] = x4.w;
        }
    }
    __syncthreads();

    if (tid < 64) {
        const int j = tid & 31;
        const bool is_s = tid < 32;
        float c0 = is_s ? bs[j] : be[j];
        float c1 = 0.f, c2 = 0.f, c3 = 0.f;
        #pragma unroll
        for (int m = 0; m < 64; m += 4) {
            c0 = fmaf(h_s[m],   Wse_s[tid][m],   c0);
            c1 = fmaf(h_s[m+1], Wse_s[tid][m+1], c1);
            c2 = fmaf(h_s[m+2], Wse_s[tid][m+2], c2);
            c3 = fmaf(h_s[m+3], Wse_s[tid][m+3], c3);
        }
        float acc = (c0 + c1) + (c2 + c3);

        float n2 = acc * acc;
        #pragma unroll
        for (int off = 16; off >= 1; off >>= 1) n2 += __shfl_xor(n2, off, 64);
        float norm = sqrtf(n2);
        float kn = acc / fmaxf(norm, 1e-12f);

        const int base = v * 32 + j;
        if (is_s) { ws[base]        = kn; ws[4096 + base] = acc; }
        else      { ws[2048 + base] = kn; ws[6144 + base] = acc; }
    }
}

// ---------------------------------------------------------------------------
// Kernel 1b: Gram tables G_w[a][b] = k_w[a].k_w[b], [64][64] in ws.
// ---------------------------------------------------------------------------
__global__ __launch_bounds__(256) void gram_kernel(float* __restrict__ ws)
{
    const int w   = blockIdx.x & 1;
    const int seg = blockIdx.x >> 1;
    const int tid = threadIdx.x;
    __shared__ float k_s[64][33];
    const float* kb = ws + w * 2048;
    for (int i = tid; i < 2048; i += 256) k_s[i >> 5][i & 31] = kb[i];
    __syncthreads();
    const int a  = seg * 16 + (tid >> 4);
    const int b0 = (tid & 15) << 2;
    float* Gw = ws + 8192 + w * 4096 + a * 64;
    #pragma unroll
    for (int bb = 0; bb < 4; ++bb) {
        const int bcol = b0 + bb;
        float acc0 = 0.f, acc1 = 0.f;
        #pragma unroll
        for (int m = 0; m < 32; m += 2) {
            acc0 = fmaf(k_s[a][m],     k_s[bcol][m],     acc0);
            acc1 = fmaf(k_s[a][m + 1], k_s[bcol][m + 1], acc1);
        }
        Gw[bcol] = acc0 + acc1;
    }
}

// chunk-8 solve-matrix build (verbatim R9 math)
static __device__ __forceinline__ void build_wpack(
    const int* tj, float fb, float invL, bool is_e, bool is_last, float* Wp,
    const float* __restrict__ Gg)
{
    float f[8];
    #pragma unroll
    for (int j = 0; j < 8; ++j) f[j] = is_e ? (fb + (float)j * invL) : 1.0f;
    if (is_last) f[7] = 0.0f;     // position 2047 is the query, not a write

    float g[28];
    #pragma unroll
    for (int j = 0; j < 7; ++j)
        #pragma unroll
        for (int m = j + 1; m < 8; ++m) g[GIX(j, m)] = Gg[tj[j] * 64 + tj[m]];

    #pragma unroll
    for (int m = 0; m < 8; ++m) {
        float col[8];
        col[m] = f[m];
        #pragma unroll
        for (int j = 6; j >= 0; --j) {
            if (j < m) {
                float acc = 0.0f;
                #pragma unroll
                for (int p = 1; p < 8; ++p)
                    if (p > j && p <= m) acc = fmaf(g[GIX(j, p)], col[p], acc);
                col[j] = -f[j] * acc;
            }
        }
        #pragma unroll
        for (int j = 0; j < 8; ++j)
            if (j <= m) Wp[OM(m) + j] = col[j];
    }
}

// chunk-16 state: slots 0..7 = EARLY chunk-8 (2C), slots 8..15 = LATE (2C+1)
struct C16 {
    int   tokv;      // lane-vector: tok[C*16 + (lane&15)]
    int   tk[16];    // uniform tokens (SGPR via v_readlane)
    float grow[16];  // G[tok_slot][lane]
    float R1[8];     // row l7 of W_{2C+1} (late solve)
    float R2[8];     // row l7 of W_{2C}  (early solve)
    float braw;      // shfl(u, tokv) issued 2 bodies early
    float bpp[16];   // G[tokprev_slot][tok_{l15}]  (bpermute, 1 body early)
    float gx[8];     // G[toklate_j][tokearly_{l7}] (VMEM, 1 body early)
};

// ---------------------------------------------------------------------------
// Kernel 2 (R22): FUSED CHUNK-16 bodies.
// R0..R5 post-mortem: body time = issue + ~450cyc fixed floor (invariant
// under instr count 172-270, slack, queues, broadcast mechanism). R3's
// double-work body took 1472 cyc (2x issue + ONE floor) -> floor amortizes
// with body size. So: halve serial body count (256->128) by fusing each
// chunk-8 pair into one body. One braw bpermute gathers 16 t's; 16-wide
// cross-chunk corr (same linear identity); intra-body coupling
// s_early = W_early (t_early - Gx^T s_late), Gx fetched as a token-pure
// VMEM gather one body ahead. W tables / prologue / LDS layout unchanged.
// ---------------------------------------------------------------------------
__global__ __launch_bounds__(128) void scan_kernel(
    const int* __restrict__ seq, const float* __restrict__ ws,
    const float* __restrict__ Wrp, const float* __restrict__ brp,
    const float* __restrict__ Wo, const float* __restrict__ bo,
    float* __restrict__ out)
{
    const int b    = blockIdx.x;
    const int tid  = threadIdx.x;        // 0..127
    const int w    = tid >> 6;           // wave: 0 = s-branch, 1 = e-branch
    const int lane = tid & 63;
    const int l7   = lane & 7;
    const int l15  = lane & 15;
    const bool is_e = (w == 1);

    __shared__ __align__(16) float Wlds[2][256][8][8];   // 128 KB
    __shared__ __align__(16) int   toklds[SEQLEN];       // 8 KB (prologue only)
    __shared__ float wacc_s[2][64];
    __shared__ float r_s[64];
    __shared__ float t1_s[64];

    const float* Gg = ws + 8192 + w * 4096;
    const int*   sq = seq + b * SEQLEN;

    // ---- stage token sequence ----
    {
        const int4* sq4 = (const int4*)sq;
        int4* tl4 = (int4*)toklds;
        #pragma unroll
        for (int i = 0; i < 4; ++i) tl4[tid + i * 128] = sq4[tid + i * 128];
    }
    __syncthreads();

    // ---- precompute chunk-8 W row-tables (unchanged) ----
    {
        const float invL = 1.0f / (float)SEQLEN;
        #pragma unroll
        for (int qq = 0; qq < 4; ++qq) {
            const int c = lane + (qq << 6);
            int tj[8];
            #pragma unroll
            for (int j = 0; j < 8; ++j) tj[j] = toklds[c * 8 + j];
            float Wp[36];
            build_wpack(tj, (float)(8 * c + 1) * invL, invL, is_e, c == 255, Wp, Gg);
            const int cx = c & 7;
            #pragma unroll
            for (int i = 0; i < 8; ++i) {
                float r[8];
                #pragma unroll
                for (int m = 0; m < 8; ++m) r[m] = (m >= i) ? Wp[OM(m) + i] : 0.0f;
                float4* dst = (float4*)&Wlds[w][c][i ^ cx][0];
                dst[0] = make_float4(r[0], r[1], r[2], r[3]);
                dst[1] = make_float4(r[4], r[5], r[6], r[7]);
            }
        }
    }
    __syncthreads();

    // ---- serial backward sweep: 128 fused chunk-16 bodies ----
    C16 A, B;
    float u, wc0 = 0.f, wc1 = 0.f, wc2 = 0.f, wc3 = 0.f;
    float sp[16];
    int tv2;

    // prologue: chunk-16 #127 fully; #126 tokens + braw; #125 tokens
    A.tokv = sq[127 * 16 + l15];
    B.tokv = sq[126 * 16 + l15];
    tv2    = sq[125 * 16 + l15];
    #pragma unroll
    for (int j = 0; j < 16; ++j) A.tk[j] = RLI(A.tokv, j);
    #pragma unroll
    for (int j = 0; j < 16; ++j) A.grow[j] = Gg[A.tk[j] * 64 + lane];
    {
        const float4* rp = (const float4*)&Wlds[w][255][l7 ^ 7][0];
        float4 lo = rp[0], hi = rp[1];
        A.R1[0]=lo.x; A.R1[1]=lo.y; A.R1[2]=lo.z; A.R1[3]=lo.w;
        A.R1[4]=hi.x; A.R1[5]=hi.y; A.R1[6]=hi.z; A.R1[7]=hi.w;
        const float4* rq = (const float4*)&Wlds[w][254][l7 ^ 6][0];
        float4 lo2 = rq[0], hi2 = rq[1];
        A.R2[0]=lo2.x; A.R2[1]=lo2.y; A.R2[2]=lo2.z; A.R2[3]=lo2.w;
        A.R2[4]=hi2.x; A.R2[5]=hi2.y; A.R2[6]=hi2.z; A.R2[7]=hi2.w;
    }
    u = Gg[A.tk[15] * 64 + lane];          // query token = position 2047
    A.braw = __shfl(u, A.tokv, 64);        // exact (no prior chunk)
    B.braw = __shfl(u, B.tokv, 64);        // misses chunk 127 -> B.bpp
    #pragma unroll
    for (int j = 0; j < 16; ++j) A.bpp[j] = 0.0f;
    {
        int addrE = __shfl(A.tokv, l7, 64);
        #pragma unroll
        for (int j = 0; j < 8; ++j) A.gx[j] = Gg[A.tk[8 + j] * 64 + addrE];
    }
    #pragma unroll
    for (int j = 0; j < 16; ++j) sp[j] = 0.0f;

    auto body16 = [&](C16& cur, C16& nxt, int C) {
        const int cm1 = (C > 0) ? C - 1 : 0;
        const int cm3 = (C > 2) ? C - 3 : 0;

        // ---- spine head: corr over previous chunk-16 (16 FMA) ----
        float q0 = fmaf(cur.bpp[1],  sp[1],  cur.bpp[0]  * sp[0]);
        float q1 = fmaf(cur.bpp[3],  sp[3],  cur.bpp[2]  * sp[2]);
        float q2 = fmaf(cur.bpp[5],  sp[5],  cur.bpp[4]  * sp[4]);
        float q3 = fmaf(cur.bpp[7],  sp[7],  cur.bpp[6]  * sp[6]);
        float q4 = fmaf(cur.bpp[9],  sp[9],  cur.bpp[8]  * sp[8]);
        float q5 = fmaf(cur.bpp[11], sp[11], cur.bpp[10] * sp[10]);
        float q6 = fmaf(cur.bpp[13], sp[13], cur.bpp[12] * sp[12]);
        float q7 = fmaf(cur.bpp[15], sp[15], cur.bpp[14] * sp[14]);
        float tl = cur.braw - (((q0 + q1) + (q2 + q3)) + ((q4 + q5) + (q6 + q7)));

        // ---- late t broadcast (slots 8..15) + own early t ----
        float tL0 = SWZF(tl, 8),  tL1 = SWZF(tl, 9),  tL2 = SWZF(tl, 10), tL3 = SWZF(tl, 11);
        float tL4 = SWZF(tl, 12), tL5 = SWZF(tl, 13), tL6 = SWZF(tl, 14), tL7 = SWZF(tl, 15);
        float tE  = SWZE(tl);                       // t at early slot l7

        // ---- prefetch chunk C-1 into nxt (off-spine filler) ----
        #pragma unroll
        for (int j = 0; j < 16; ++j) nxt.bpp[j] = __shfl(cur.grow[j], nxt.tokv, 64);
        #pragma unroll
        for (int j = 0; j < 16; ++j) nxt.tk[j] = RLI(nxt.tokv, j);
        #pragma unroll
        for (int j = 0; j < 16; ++j) nxt.grow[j] = Gg[nxt.tk[j] * 64 + lane];
        {
            const int c8a = 2 * cm1 + 1, c8b = 2 * cm1;
            const float4* rp = (const float4*)&Wlds[w][c8a][l7 ^ (c8a & 7)][0];
            float4 lo = rp[0], hi = rp[1];
            nxt.R1[0]=lo.x; nxt.R1[1]=lo.y; nxt.R1[2]=lo.z; nxt.R1[3]=lo.w;
            nxt.R1[4]=hi.x; nxt.R1[5]=hi.y; nxt.R1[6]=hi.z; nxt.R1[7]=hi.w;
            const float4* rq = (const float4*)&Wlds[w][c8b][l7 ^ (c8b & 7)][0];
            float4 lo2 = rq[0], hi2 = rq[1];
            nxt.R2[0]=lo2.x; nxt.R2[1]=lo2.y; nxt.R2[2]=lo2.z; nxt.R2[3]=lo2.w;
            nxt.R2[4]=hi2.x; nxt.R2[5]=hi2.y; nxt.R2[6]=hi2.z; nxt.R2[7]=hi2.w;
        }
        {
            int addrE = __shfl(nxt.tokv, l7, 64);
            #pragma unroll
            for (int j = 0; j < 8; ++j) nxt.gx[j] = Gg[nxt.tk[8 + j] * 64 + addrE];
        }
        int tv3 = sq[cm3 * 16 + l15];

        // ---- phase 1 (late sub-chunk): s1 = W_{2C+1} t_late ----
        const float* R1 = cur.R1;
        float a0 = fmaf(R1[1], tL1, R1[0] * tL0);
        float a1 = fmaf(R1[3], tL3, R1[2] * tL2);
        float a2 = fmaf(R1[5], tL5, R1[4] * tL4);
        float a3 = fmaf(R1[7], tL7, R1[6] * tL6);
        float sd1 = (a0 + a1) + (a2 + a3);
        float s10 = SWZF(sd1, 0), s11 = SWZF(sd1, 1), s12 = SWZF(sd1, 2), s13 = SWZF(sd1, 3);
        float s14 = SWZF(sd1, 4), s15 = SWZF(sd1, 5), s16 = SWZF(sd1, 6), s17 = SWZF(sd1, 7);

        // ---- phase 2 (early sub-chunk): t' = tE - Gx^T s1; s2 = W_{2C} t' ----
        const float* gx = cur.gx;
        float b0 = fmaf(gx[1], s11, gx[0] * s10);
        float b1 = fmaf(gx[3], s13, gx[2] * s12);
        float b2 = fmaf(gx[5], s15, gx[4] * s14);
        float b3 = fmaf(gx[7], s17, gx[6] * s16);
        float tpl = tE - ((b0 + b1) + (b2 + b3));
        float tP0 = SWZF(tpl, 0), tP1 = SWZF(tpl, 1), tP2 = SWZF(tpl, 2), tP3 = SWZF(tpl, 3);
        float tP4 = SWZF(tpl, 4), tP5 = SWZF(tpl, 5), tP6 = SWZF(tpl, 6), tP7 = SWZF(tpl, 7);

        const float* R2 = cur.R2;
        float e0 = fmaf(R2[1], tP1, R2[0] * tP0);
        float e1 = fmaf(R2[3], tP3, R2[2] * tP2);
        float e2 = fmaf(R2[5], tP5, R2[4] * tP4);
        float e3 = fmaf(R2[7], tP7, R2[6] * tP6);
        float sd2 = (e0 + e1) + (e2 + e3);
        float s20 = SWZF(sd2, 0), s21 = SWZF(sd2, 1), s22 = SWZF(sd2, 2), s23 = SWZF(sd2, 3);
        float s24 = SWZF(sd2, 4), s25 = SWZF(sd2, 5), s26 = SWZF(sd2, 6), s27 = SWZF(sd2, 7);

        // ---- u update (16 FMA), then braw for chunk C-2 (2-body slack) ----
        float dA = fmaf(cur.grow[8],  s10, fmaf(cur.grow[9],  s11, fmaf(cur.grow[10], s12, cur.grow[11] * s13)));
        float dB = fmaf(cur.grow[12], s14, fmaf(cur.grow[13], s15, fmaf(cur.grow[14], s16, cur.grow[15] * s17)));
        float dC = fmaf(cur.grow[0],  s20, fmaf(cur.grow[1],  s21, fmaf(cur.grow[2],  s22, cur.grow[3]  * s23)));
        float dD = fmaf(cur.grow[4],  s24, fmaf(cur.grow[5],  s25, fmaf(cur.grow[6],  s26, cur.grow[7]  * s27)));
        u -= (dA + dB) + (dC + dD);
        cur.braw = __shfl(u, tv2, 64);

        // ---- wacc[tok_slot] += s_slot (lane = token; 4 partials) ----
        wc0 += (lane == cur.tk[8])  ? s10 : 0.0f;
        wc1 += (lane == cur.tk[9])  ? s11 : 0.0f;
        wc2 += (lane == cur.tk[10]) ? s12 : 0.0f;
        wc3 += (lane == cur.tk[11]) ? s13 : 0.0f;
        wc0 += (lane == cur.tk[12]) ? s14 : 0.0f;
        wc1 += (lane == cur.tk[13]) ? s15 : 0.0f;
        wc2 += (lane == cur.tk[14]) ? s16 : 0.0f;
        wc3 += (lane == cur.tk[15]) ? s17 : 0.0f;
        wc0 += (lane == cur.tk[0])  ? s20 : 0.0f;
        wc1 += (lane == cur.tk[1])  ? s21 : 0.0f;
        wc2 += (lane == cur.tk[2])  ? s22 : 0.0f;
        wc3 += (lane == cur.tk[3])  ? s23 : 0.0f;
        wc0 += (lane == cur.tk[4])  ? s24 : 0.0f;
        wc1 += (lane == cur.tk[5])  ? s25 : 0.0f;
        wc2 += (lane == cur.tk[6])  ? s26 : 0.0f;
        wc3 += (lane == cur.tk[7])  ? s27 : 0.0f;

        // ---- rotate ----
        cur.tokv = tv2; tv2 = tv3;
        sp[8]  = s10; sp[9]  = s11; sp[10] = s12; sp[11] = s13;
        sp[12] = s14; sp[13] = s15; sp[14] = s16; sp[15] = s17;
        sp[0]  = s20; sp[1]  = s21; sp[2]  = s22; sp[3]  = s23;
        sp[4]  = s24; sp[5]  = s25; sp[6]  = s26; sp[7]  = s27;
    };

    for (int C = 127; C >= 1; C -= 2) {
        body16(A, B, C);
        body16(B, A, C - 1);
    }

    wacc_s[w][lane] = (wc0 + wc1) + (wc2 + wc3);
    __syncthreads();

    // r[w2][rho] = sum_tok wacc[w2][tok] * v[w2][tok][rho]
    if (tid < 64) {
        const int w2  = tid >> 5;
        const int rho = tid & 31;
        const float* vv = ws + 4096 + w2 * 2048;
        const float* wa = &wacc_s[w2][0];
        float acc = 0.0f;
        #pragma unroll 8
        for (int tok = 0; tok < 64; ++tok) acc = fmaf(wa[tok], vv[tok * 32 + rho], acc);
        r_s[tid] = acc;
    }
    __syncthreads();

    // out = (r @ Wrp.T + brp) @ Wo.T + bo
    if (tid < 64) {
        float acc = brp[tid];
        #pragma unroll 8
        for (int m = 0; m < 64; ++m) acc = fmaf(Wrp[tid * 64 + m], r_s[m], acc);
        t1_s[tid] = acc;
    }
    __syncthreads();
    if (tid < 64) {
        float acc = bo[tid];
        #pragma unroll 8
        for (int m = 0; m < 64; ++m) acc = fmaf(Wo[tid * 64 + m], t1_s[m], acc);
        out[b * 64 + tid] = acc;
    }
}

extern "C" void kernel_launch(void* const* d_in, const int* in_sizes, int n_in,
                              void* d_out, int out_size, void* d_ws, size_t ws_size,
                              hipStream_t stream)
{
    const int*   seq   = (const int*)  d_in[0];
    const float* embed = (const float*)d_in[1];
    const float* W1    = (const float*)d_in[2];
    const float* b1    = (const float*)d_in[3];
    const float* W2    = (const float*)d_in[4];
    const float* b2    = (const float*)d_in[5];
    const float* ln_g  = (const float*)d_in[6];
    const float* ln_b  = (const float*)d_in[7];
    const float* Ws    = (const float*)d_in[8];
    const float* bs    = (const float*)d_in[9];
    const float* We    = (const float*)d_in[10];
    const float* be    = (const float*)d_in[11];
    const float* Wrp   = (const float*)d_in[12];
    const float* brp   = (const float*)d_in[13];
    const float* Wo    = (const float*)d_in[14];
    const float* bo    = (const float*)d_in[15];
    float* ws  = (float*)d_ws;
    float* out = (float*)d_out;

    hipLaunchKernelGGL(vocab_kernel, dim3(VOCAB), dim3(256), 0, stream,
                       embed, W1, b1, W2, b2, ln_g, ln_b, Ws, bs, We, be, ws);
    hipLaunchKernelGGL(gram_kernel, dim3(8), dim3(256), 0, stream, ws);
    hipLaunchKernelGGL(scan_kernel, dim3(BATCH), dim3(128), 0, stream,
                       seq, ws, Wrp, brp, Wo, bo, out);
}